// Round 4
// baseline (293.224 us; speedup 1.0000x reference)
//
#include <hip/hip_runtime.h>
#include <hip/hip_bf16.h>
#include <math.h>

#define B_   256
#define L_   196
#define ENC_ 2048
#define DEC_ 512
#define HID_ 512

typedef __attribute__((ext_vector_type(8))) short short8v;
typedef __attribute__((ext_vector_type(4))) short short4v;
typedef __attribute__((ext_vector_type(4))) float f32x4;

static __device__ __forceinline__ short f2bf(float x) {
    unsigned u = __float_as_uint(x);
    u += 0x7fffu + ((u >> 16) & 1u);   // round-to-nearest-even
    return (short)(u >> 16);
}

// ---------------------------------------------------------------------------
// Wf (f32 [512,2048]) -> bf16, stored PRE-SWIZZLED: within each row, 16B unit
// U holds original unit U ^ (n&7).  Then the GEMM can stage with linear
// global_load_lds and read LDS with the same XOR (T2, conflict-free).
// ---------------------------------------------------------------------------
__global__ __launch_bounds__(256) void kconvert(const float* __restrict__ Wf,
                                                short* __restrict__ wfbf) {
    int idx = (blockIdx.x * 256 + threadIdx.x) * 4;   // over 512*2048 = 1M elems
    int n  = idx >> 11;
    int e0 = idx & 2047;
    float4 f = *(const float4*)(Wf + idx);
    short4v h;
    h.x = f2bf(f.x); h.y = f2bf(f.y); h.z = f2bf(f.z); h.w = f2bf(f.w);
    int unit = (e0 >> 3) ^ (n & 7);
    int off  = n * 2048 + unit * 8 + (e0 & 7);
    *(short4v*)(wfbf + off) = h;
}

// ---------------------------------------------------------------------------
// hid_emb[b,h] = hidden[b,:] . Wh[h,:] + bh[h]     (256x512, K=512, fp32)
// 8 batches per block so each Wh row-stream is reused 8x.
// ---------------------------------------------------------------------------
__global__ __launch_bounds__(512) void khid(const float* __restrict__ hidden,
                                            const float* __restrict__ Wh,
                                            const float* __restrict__ bh,
                                            float* __restrict__ hid_emb) {
    __shared__ float hs[8][512];
    int t = threadIdx.x;
    int bg = blockIdx.x * 8;
    #pragma unroll
    for (int i = 0; i < 8; ++i) hs[i][t] = hidden[(size_t)(bg + i) * 512 + t];
    __syncthreads();
    float acc[8] = {0.f,0.f,0.f,0.f,0.f,0.f,0.f,0.f};
    const float4* wrow = (const float4*)(Wh + (size_t)t * 512);
    #pragma unroll 4
    for (int d4 = 0; d4 < 128; ++d4) {
        float4 w = wrow[d4];
        int d = d4 * 4;
        #pragma unroll
        for (int i = 0; i < 8; ++i)
            acc[i] += w.x * hs[i][d] + w.y * hs[i][d+1] + w.z * hs[i][d+2] + w.w * hs[i][d+3];
    }
    float bhv = bh[t];
    #pragma unroll
    for (int i = 0; i < 8; ++i)
        hid_emb[(size_t)(bg + i) * 512 + t] = acc[i] + bhv;
}

// ---------------------------------------------------------------------------
// Fused score GEMM: score[m] = sum_h relu(feat[m,:].Wf[h,:] + bf[h]
//                                          + hid_emb[b(m),h]) * We[h] + be
// M-tile 64, N = 512 (full), BK = 64.  4 waves, each wave 64x128,
// mfma_f32_16x16x32_bf16, acc 4x8 frags.
// ---------------------------------------------------------------------------
__global__ __launch_bounds__(256, 2) void kscore(
    const float* __restrict__ feat, const short* __restrict__ wfbf,
    const float* __restrict__ bf, const float* __restrict__ hid_emb,
    const float* __restrict__ We, const float* __restrict__ be,
    float* __restrict__ score)
{
    __shared__ short lds_b[512 * 64];   // 64 KB, swizzled [n][k]
    __shared__ short lds_a[64 * 64];    //  8 KB, swizzled [r][k]
    __shared__ float score_s[4][64];

    const int tid  = threadIdx.x;
    const int wave = tid >> 6;
    const int lane = tid & 63;
    const int g    = lane >> 4;
    const int c    = lane & 15;
    const int m0   = blockIdx.x * 64;

    f32x4 acc[4][8];
    #pragma unroll
    for (int i = 0; i < 4; ++i)
        #pragma unroll
        for (int j = 0; j < 8; ++j)
            acc[i][j] = (f32x4)0.f;

    for (int kt = 0; kt < 32; ++kt) {
        const int k0 = kt * 64;
        // ---- stage A: f32 -> bf16, XOR-swizzled reg-staging ----
        #pragma unroll
        for (int i = 0; i < 4; ++i) {
            int ch = tid + i * 256;            // 1024 chunks of 4 floats
            int r  = ch >> 4;
            int c4 = ch & 15;
            float4 f = *(const float4*)(feat + (size_t)(m0 + r) * ENC_ + k0 + c4 * 4);
            short4v h;
            h.x = f2bf(f.x); h.y = f2bf(f.y); h.z = f2bf(f.z); h.w = f2bf(f.w);
            int unit = (c4 >> 1) ^ (r & 7);
            int boff = r * 128 + unit * 16 + (c4 & 1) * 8;
            *(short4v*)((char*)lds_a + boff) = h;
        }
        // ---- stage B: linear global_load_lds from pre-swizzled source ----
        #pragma unroll
        for (int j = 0; j < 16; ++j) {
            int ulin = wave * 1024 + j * 64 + lane;   // 16B unit index
            int n = ulin >> 3;
            int u = ulin & 7;
            const short* gp = wfbf + (size_t)n * ENC_ + k0 + u * 8;
            short* lp = lds_b + (size_t)(wave * 1024 + j * 64) * 8;
            __builtin_amdgcn_global_load_lds(
                (const __attribute__((address_space(1))) void*)gp,
                (__attribute__((address_space(3))) void*)lp, 16, 0, 0);
        }
        __syncthreads();
        // ---- compute ----
        #pragma unroll
        for (int kf = 0; kf < 2; ++kf) {
            short8v af[4], bq[8];
            #pragma unroll
            for (int mi = 0; mi < 4; ++mi) {
                int row = mi * 16 + c;                 // A: row = lane&15
                int un  = (kf * 4 + g) ^ (row & 7);
                af[mi] = *(const short8v*)((const char*)lds_a + row * 128 + un * 16);
            }
            #pragma unroll
            for (int ni = 0; ni < 8; ++ni) {
                int n  = wave * 128 + ni * 16 + c;     // B: col = lane&15
                int un = (kf * 4 + g) ^ (n & 7);
                bq[ni] = *(const short8v*)((const char*)lds_b + n * 128 + un * 16);
            }
            #pragma unroll
            for (int mi = 0; mi < 4; ++mi)
                #pragma unroll
                for (int ni = 0; ni < 8; ++ni)
                    acc[mi][ni] = __builtin_amdgcn_mfma_f32_16x16x32_bf16(
                        af[mi], bq[ni], acc[mi][ni], 0, 0, 0);
        }
        __syncthreads();
    }

    // ---- fused epilogue: +bf +hid_emb, relu, dot We, reduce over n ----
    float wev[8], bfv[8];
    #pragma unroll
    for (int ni = 0; ni < 8; ++ni) {
        int n = wave * 128 + ni * 16 + c;
        wev[ni] = We[n];
        bfv[ni] = bf[n];
    }
    #pragma unroll
    for (int mi = 0; mi < 4; ++mi) {
        float part[4] = {0.f, 0.f, 0.f, 0.f};
        #pragma unroll
        for (int j = 0; j < 4; ++j) {
            int row  = mi * 16 + g * 4 + j;            // C/D: row=(lane>>4)*4+reg
            int bidx = (m0 + row) / 196;
            const float* hrow = hid_emb + (size_t)bidx * 512;
            #pragma unroll
            for (int ni = 0; ni < 8; ++ni) {
                int n = wave * 128 + ni * 16 + c;
                float v = acc[mi][ni][j] + bfv[ni] + hrow[n];
                v = fmaxf(v, 0.f);
                part[j] += v * wev[ni];
            }
        }
        #pragma unroll
        for (int j = 0; j < 4; ++j) {
            float p = part[j];
            p += __shfl_xor(p, 1, 16);
            p += __shfl_xor(p, 2, 16);
            p += __shfl_xor(p, 4, 16);
            p += __shfl_xor(p, 8, 16);
            if (c == 0) score_s[wave][mi * 16 + g * 4 + j] = p;
        }
    }
    __syncthreads();
    if (tid < 64) {
        float s = score_s[0][tid] + score_s[1][tid] + score_s[2][tid]
                + score_s[3][tid] + be[0];
        score[m0 + tid] = s;
    }
}

// ---------------------------------------------------------------------------
// Softmax over L=196 + output[b,e] = sum_l w[l] * feature[b,l,e].
// 2 blocks per b (each does 1024 of the 2048 columns; both recompute softmax).
// ---------------------------------------------------------------------------
__global__ __launch_bounds__(256) void kout(
    const float* __restrict__ score, const float* __restrict__ feat,
    float* __restrict__ out_o, float* __restrict__ out_w)
{
    __shared__ float wbuf[196];
    __shared__ float red[8];
    int t    = threadIdx.x;
    int b    = blockIdx.x >> 1;
    int half = blockIdx.x & 1;
    int w    = t >> 6, lane = t & 63;

    float s = (t < 196) ? score[b * 196 + t] : -1e30f;
    float m = s;
    #pragma unroll
    for (int off = 32; off >= 1; off >>= 1) m = fmaxf(m, __shfl_xor(m, off, 64));
    if (lane == 0) red[w] = m;
    __syncthreads();
    m = fmaxf(fmaxf(red[0], red[1]), fmaxf(red[2], red[3]));
    float e = (t < 196) ? __expf(s - m) : 0.f;
    float sum = e;
    #pragma unroll
    for (int off = 32; off >= 1; off >>= 1) sum += __shfl_xor(sum, off, 64);
    if (lane == 0) red[4 + w] = sum;
    __syncthreads();
    sum = red[4] + red[5] + red[6] + red[7];
    float wt = e / sum;
    if (t < 196) {
        wbuf[t] = wt;
        if (half == 0) out_w[b * 196 + t] = wt;
    }
    __syncthreads();

    int e0 = half * 1024 + t * 4;
    float4 acc = make_float4(0.f, 0.f, 0.f, 0.f);
    const float* fb = feat + (size_t)b * L_ * ENC_ + e0;
    #pragma unroll 4
    for (int l = 0; l < 196; ++l) {
        float4 v = *(const float4*)(fb + (size_t)l * ENC_);
        float wl = wbuf[l];
        acc.x += wl * v.x; acc.y += wl * v.y; acc.z += wl * v.z; acc.w += wl * v.w;
    }
    *(float4*)(out_o + (size_t)b * ENC_ + e0) = acc;
}

extern "C" void kernel_launch(void* const* d_in, const int* in_sizes, int n_in,
                              void* d_out, int out_size, void* d_ws, size_t ws_size,
                              hipStream_t stream) {
    (void)in_sizes; (void)n_in; (void)out_size; (void)ws_size;
    const float* feature = (const float*)d_in[0];
    const float* hidden  = (const float*)d_in[1];
    const float* Wf      = (const float*)d_in[2];
    const float* bf      = (const float*)d_in[3];
    const float* Wh      = (const float*)d_in[4];
    const float* bh      = (const float*)d_in[5];
    const float* We      = (const float*)d_in[6];
    const float* be      = (const float*)d_in[7];

    char* ws = (char*)d_ws;
    short* wfbf    = (short*)ws;                               // 2 MB
    float* hid_emb = (float*)(ws + (2u << 20));                // 512 KB
    float* score   = (float*)(ws + (2u << 20) + (512u << 10)); // 200 KB

    float* out_o = (float*)d_out;                 // [256,2048]
    float* out_w = out_o + (size_t)B_ * ENC_;     // [256,196]

    kconvert<<<dim3(1024), dim3(256), 0, stream>>>(Wf, wfbf);
    khid<<<dim3(32), dim3(512), 0, stream>>>(hidden, Wh, bh, hid_emb);
    kscore<<<dim3(784), dim3(256), 0, stream>>>(feature, wfbf, bf, hid_emb, We, be, score);
    kout<<<dim3(512), dim3(256), 0, stream>>>(score, feature, (float*)d_out, out_w);
}

// Round 6
// 280.309 us; speedup vs baseline: 1.0461x; 1.0461x over previous
//
#include <hip/hip_runtime.h>
#include <hip/hip_bf16.h>
#include <math.h>

#define B_   256
#define L_   196
#define ENC_ 2048
#define DEC_ 512
#define HID_ 512

typedef __attribute__((ext_vector_type(8))) short short8v;
typedef __attribute__((ext_vector_type(4))) short short4v;
typedef __attribute__((ext_vector_type(4))) float f32x4;

static __device__ __forceinline__ short f2bf(float x) {
    unsigned u = __float_as_uint(x);
    u += 0x7fffu + ((u >> 16) & 1u);   // round-to-nearest-even
    return (short)(u >> 16);
}

// ---------------------------------------------------------------------------
// Wf (f32 [512,2048]) -> bf16, stored PRE-SWIZZLED: within each row, 16B unit
// U holds original unit U ^ (n&7).  Then the GEMM can stage with linear
// global_load_lds and read LDS with the same XOR (T2, conflict-free).
// ---------------------------------------------------------------------------
__global__ __launch_bounds__(256) void kconvert(const float* __restrict__ Wf,
                                                short* __restrict__ wfbf) {
    int idx = (blockIdx.x * 256 + threadIdx.x) * 4;   // over 512*2048 = 1M elems
    int n  = idx >> 11;
    int e0 = idx & 2047;
    float4 f = *(const float4*)(Wf + idx);
    short4v h;
    h.x = f2bf(f.x); h.y = f2bf(f.y); h.z = f2bf(f.z); h.w = f2bf(f.w);
    int unit = (e0 >> 3) ^ (n & 7);
    int off  = n * 2048 + unit * 8 + (e0 & 7);
    *(short4v*)(wfbf + off) = h;
}

// ---------------------------------------------------------------------------
// hid_emb[b,h] = hidden[b,:] . Wh[h,:] + bh[h]     (256x512, K=512, fp32)
// ---------------------------------------------------------------------------
__global__ __launch_bounds__(512) void khid(const float* __restrict__ hidden,
                                            const float* __restrict__ Wh,
                                            const float* __restrict__ bh,
                                            float* __restrict__ hid_emb) {
    __shared__ float hs[8][512];
    int t = threadIdx.x;
    int bg = blockIdx.x * 8;
    #pragma unroll
    for (int i = 0; i < 8; ++i) hs[i][t] = hidden[(size_t)(bg + i) * 512 + t];
    __syncthreads();
    float acc[8] = {0.f,0.f,0.f,0.f,0.f,0.f,0.f,0.f};
    const float4* wrow = (const float4*)(Wh + (size_t)t * 512);
    #pragma unroll 4
    for (int d4 = 0; d4 < 128; ++d4) {
        float4 w = wrow[d4];
        int d = d4 * 4;
        #pragma unroll
        for (int i = 0; i < 8; ++i)
            acc[i] += w.x * hs[i][d] + w.y * hs[i][d+1] + w.z * hs[i][d+2] + w.w * hs[i][d+3];
    }
    float bhv = bh[t];
    #pragma unroll
    for (int i = 0; i < 8; ++i)
        hid_emb[(size_t)(bg + i) * 512 + t] = acc[i] + bhv;
}

// ---------------------------------------------------------------------------
// Fused score GEMM v3: 64M x 512N block tile, BK=64, 512 threads / 8 waves,
// each wave owning a 64x64 sub-tile (acc 4x4 = 64 regs).  ~<=128 VGPR/wave
// -> 4 waves/SIMD (16 waves/CU), 2x the occupancy of the 243us v1 so the
// per-K-step vmcnt(0)+barrier drain is hidden by co-resident waves.
// v3 fixes v2's bug: B-stage now covers all 4096 16B units (8 iters x 512
// threads), and uses the explicit wave-uniform LDS-base form.
// ---------------------------------------------------------------------------
__global__ __launch_bounds__(512, 4) void kscore(
    const float* __restrict__ feat, const short* __restrict__ wfbf,
    const float* __restrict__ bf, const float* __restrict__ hid_emb,
    const float* __restrict__ We, const float* __restrict__ be,
    float* __restrict__ score)
{
    __shared__ short lds_b[512 * 64];   // 64 KB, swizzled [n][k]
    __shared__ short lds_a[64 * 64];    //  8 KB, swizzled [r][k]
    __shared__ float score_s[8][64];

    const int tid  = threadIdx.x;
    const int wave = tid >> 6;
    const int lane = tid & 63;
    const int g    = lane >> 4;
    const int c    = lane & 15;
    const int m0   = blockIdx.x * 64;

    f32x4 acc[4][4];
    #pragma unroll
    for (int i = 0; i < 4; ++i)
        #pragma unroll
        for (int j = 0; j < 4; ++j)
            acc[i][j] = (f32x4)0.f;

    for (int kt = 0; kt < 32; ++kt) {
        const int k0 = kt * 64;
        // ---- stage A: f32 -> bf16, XOR-swizzled reg-staging (2 chunks/thr) ----
        #pragma unroll
        for (int i = 0; i < 2; ++i) {
            int ch = tid + i * 512;            // 1024 chunks of 4 floats
            int r  = ch >> 4;
            int c4 = ch & 15;
            float4 f = *(const float4*)(feat + (size_t)(m0 + r) * ENC_ + k0 + c4 * 4);
            short4v h;
            h.x = f2bf(f.x); h.y = f2bf(f.y); h.z = f2bf(f.z); h.w = f2bf(f.w);
            int unit = (c4 >> 1) ^ (r & 7);
            int boff = r * 128 + unit * 16 + (c4 & 1) * 8;
            *(short4v*)((char*)lds_a + boff) = h;
        }
        // ---- stage B: linear global_load_lds from pre-swizzled source ----
        // 4096 16B units total: 8 iters x 8 waves x 64 lanes.
        #pragma unroll
        for (int j = 0; j < 8; ++j) {
            int ubase = j * 512 + wave * 64;          // wave-uniform unit base
            int ulin  = ubase + lane;                 // this lane's unit
            int n = ulin >> 3;
            int u = ulin & 7;
            const short* gp = wfbf + (size_t)n * ENC_ + k0 + u * 8;
            short* lp = lds_b + (size_t)ubase * 8;    // uniform base; HW adds lane*16B
            __builtin_amdgcn_global_load_lds(
                (const __attribute__((address_space(1))) void*)gp,
                (__attribute__((address_space(3))) void*)lp, 16, 0, 0);
        }
        __syncthreads();
        // ---- compute ----
        #pragma unroll
        for (int kf = 0; kf < 2; ++kf) {
            short8v af[4], bq[4];
            #pragma unroll
            for (int mi = 0; mi < 4; ++mi) {
                int row = mi * 16 + c;                 // A: row = lane&15
                int un  = (kf * 4 + g) ^ (row & 7);
                af[mi] = *(const short8v*)((const char*)lds_a + row * 128 + un * 16);
            }
            #pragma unroll
            for (int ni = 0; ni < 4; ++ni) {
                int n  = wave * 64 + ni * 16 + c;      // B: col = lane&15
                int un = (kf * 4 + g) ^ (n & 7);
                bq[ni] = *(const short8v*)((const char*)lds_b + n * 128 + un * 16);
            }
            #pragma unroll
            for (int mi = 0; mi < 4; ++mi)
                #pragma unroll
                for (int ni = 0; ni < 4; ++ni)
                    acc[mi][ni] = __builtin_amdgcn_mfma_f32_16x16x32_bf16(
                        af[mi], bq[ni], acc[mi][ni], 0, 0, 0);
        }
        __syncthreads();
    }

    // ---- fused epilogue: +bf +hid_emb, relu, dot We, reduce over n ----
    float wev[4], bfv[4];
    #pragma unroll
    for (int ni = 0; ni < 4; ++ni) {
        int n = wave * 64 + ni * 16 + c;
        wev[ni] = We[n];
        bfv[ni] = bf[n];
    }
    #pragma unroll
    for (int mi = 0; mi < 4; ++mi) {
        float part[4] = {0.f, 0.f, 0.f, 0.f};
        #pragma unroll
        for (int j = 0; j < 4; ++j) {
            int row  = mi * 16 + g * 4 + j;            // C/D: row=(lane>>4)*4+reg
            int bidx = (m0 + row) / 196;
            const float* hrow = hid_emb + (size_t)bidx * 512;
            #pragma unroll
            for (int ni = 0; ni < 4; ++ni) {
                int n = wave * 64 + ni * 16 + c;
                float v = acc[mi][ni][j] + bfv[ni] + hrow[n];
                v = fmaxf(v, 0.f);
                part[j] += v * wev[ni];
            }
        }
        #pragma unroll
        for (int j = 0; j < 4; ++j) {
            float p = part[j];
            p += __shfl_xor(p, 1, 16);
            p += __shfl_xor(p, 2, 16);
            p += __shfl_xor(p, 4, 16);
            p += __shfl_xor(p, 8, 16);
            if (c == 0) score_s[wave][mi * 16 + g * 4 + j] = p;
        }
    }
    __syncthreads();
    if (tid < 64) {
        float s = be[0];
        #pragma unroll
        for (int w = 0; w < 8; ++w) s += score_s[w][tid];
        score[m0 + tid] = s;
    }
}

// ---------------------------------------------------------------------------
// Softmax over L=196 + output[b,e] = sum_l w[l] * feature[b,l,e].
// 2 blocks per b (each does 1024 of the 2048 columns; both recompute softmax).
// ---------------------------------------------------------------------------
__global__ __launch_bounds__(256) void kout(
    const float* __restrict__ score, const float* __restrict__ feat,
    float* __restrict__ out_o, float* __restrict__ out_w)
{
    __shared__ float wbuf[196];
    __shared__ float red[8];
    int t    = threadIdx.x;
    int b    = blockIdx.x >> 1;
    int half = blockIdx.x & 1;
    int w    = t >> 6, lane = t & 63;

    float s = (t < 196) ? score[b * 196 + t] : -1e30f;
    float m = s;
    #pragma unroll
    for (int off = 32; off >= 1; off >>= 1) m = fmaxf(m, __shfl_xor(m, off, 64));
    if (lane == 0) red[w] = m;
    __syncthreads();
    m = fmaxf(fmaxf(red[0], red[1]), fmaxf(red[2], red[3]));
    float e = (t < 196) ? __expf(s - m) : 0.f;
    float sum = e;
    #pragma unroll
    for (int off = 32; off >= 1; off >>= 1) sum += __shfl_xor(sum, off, 64);
    if (lane == 0) red[4 + w] = sum;
    __syncthreads();
    sum = red[4] + red[5] + red[6] + red[7];
    float wt = e / sum;
    if (t < 196) {
        wbuf[t] = wt;
        if (half == 0) out_w[b * 196 + t] = wt;
    }
    __syncthreads();

    int e0 = half * 1024 + t * 4;
    float4 acc = make_float4(0.f, 0.f, 0.f, 0.f);
    const float* fb = feat + (size_t)b * L_ * ENC_ + e0;
    #pragma unroll 4
    for (int l = 0; l < 196; ++l) {
        float4 v = *(const float4*)(fb + (size_t)l * ENC_);
        float wl = wbuf[l];
        acc.x += wl * v.x; acc.y += wl * v.y; acc.z += wl * v.z; acc.w += wl * v.w;
    }
    *(float4*)(out_o + (size_t)b * ENC_ + e0) = acc;
}

extern "C" void kernel_launch(void* const* d_in, const int* in_sizes, int n_in,
                              void* d_out, int out_size, void* d_ws, size_t ws_size,
                              hipStream_t stream) {
    (void)in_sizes; (void)n_in; (void)out_size; (void)ws_size;
    const float* feature = (const float*)d_in[0];
    const float* hidden  = (const float*)d_in[1];
    const float* Wf      = (const float*)d_in[2];
    const float* bf      = (const float*)d_in[3];
    const float* Wh      = (const float*)d_in[4];
    const float* bh      = (const float*)d_in[5];
    const float* We      = (const float*)d_in[6];
    const float* be      = (const float*)d_in[7];

    char* ws = (char*)d_ws;
    short* wfbf    = (short*)ws;                               // 2 MB
    float* hid_emb = (float*)(ws + (2u << 20));                // 512 KB
    float* score   = (float*)(ws + (2u << 20) + (512u << 10)); // 200 KB

    float* out_o = (float*)d_out;                 // [256,2048]
    float* out_w = out_o + (size_t)B_ * ENC_;     // [256,196]

    kconvert<<<dim3(1024), dim3(256), 0, stream>>>(Wf, wfbf);
    khid<<<dim3(32), dim3(512), 0, stream>>>(hidden, Wh, bh, hid_emb);
    kscore<<<dim3(784), dim3(512), 0, stream>>>(feature, wfbf, bf, hid_emb, We, be, score);
    kout<<<dim3(512), dim3(256), 0, stream>>>(score, feature, (float*)d_out, out_w);
}